// Round 3
// baseline (214.234 us; speedup 1.0000x reference)
//
#include <hip/hip_runtime.h>

// IDCST2 via FFTs: out = C0 @ (x @ S1^T), M=N=4096, fp32.
//   Stage 1 (rows):  z[p][v] = DST3(x[p])[v]
//   Stage 2 (cols):  out[:,v] = DCT3(z[:,v])
//   DST-III:  s_v = (-1)^v * DCT3(reverse(x))_v  (c_0 = 0)
//   DCT-III via N-pt complex DFT (inverse Makhoul):
//     W_k = (c_k - i c_{N-k}) e^{i pi k/2N};  v = DFT_+(W)
//     y_{2n} = (Re v_n + c_0)/2 ; y_{2n+1} = (Re v_{N-1-n} + c_0)/2
//   v real => pack 2 rows (stage1) / 2 cols (stage2) per FFT as Re/Im.
//   The 1/2 scale is folded into the pack twiddle.
// FFT: radix-16 register FFT, 4096 = 16^3. Pass A entirely in registers
//   (pack fragment set == pass-A fragment set, same thread), then 2 LDS
//   exchanges (XOR-swizzled, conflict-free), 5 barriers, 32 KiB LDS.
// TRANSPOSE-FREE pipeline (2 kernels, 256 MiB HBM total):
//   intermediate z stored as 2048 column-pair PANELS: z[vp][p][c],
//   addr = vp*8192 + 2*p + c  (panel = 32 KiB contiguous = one K2 input).
//   K1 scatter-writes one float4 (2 rows x 2 cols) per panel; a 128B line
//   is completed by 8 consecutive K1 blocks -> chunked XCD swizzle puts
//   them on one XCD so lines merge dirty in its L2 (HBM write = 64 MiB).
//   K2 reads its panel fully coalesced; writes out columns as float2 per
//   row; a 128B out-line spans 16 consecutive K2 blocks -> same merge.

#define NF 4096
#define TWOPI_16384 3.8349519697141029e-4f  // 2*pi/16384
#define TWOPI_4096  1.5339807878856412e-3f  // 2*pi/4096
#define TWOPI_256   2.4543692606170259e-2f  // 2*pi/256

__device__ __forceinline__ float2 cmul(float2 a, float2 b) {
    return make_float2(a.x * b.x - a.y * b.y, a.x * b.y + a.y * b.x);
}
__device__ __forceinline__ float2 cadd(float2 a, float2 b) {
    return make_float2(a.x + b.x, a.y + b.y);
}
__device__ __forceinline__ float2 csub(float2 a, float2 b) {
    return make_float2(a.x - b.x, a.y - b.y);
}
__device__ __forceinline__ float2 muli(float2 a) {  // +i * a (positive-sign DFT)
    return make_float2(-a.y, a.x);
}

// 16-point DFT_+ in registers, natural order in/out (verified r2).
__device__ __forceinline__ void fft16(float2 f[16]) {
    float2 s[16];
#pragma unroll
    for (int b = 0; b < 4; ++b) {
        float2 x0 = f[b], x1 = f[b + 4], x2 = f[b + 8], x3 = f[b + 12];
        float2 t0 = cadd(x0, x2), t1 = csub(x0, x2);
        float2 t2 = cadd(x1, x3), t3 = csub(x1, x3);
        s[b]      = cadd(t0, t2);
        s[4 + b]  = cadd(t1, muli(t3));
        s[8 + b]  = csub(t0, t2);
        s[12 + b] = csub(t1, muli(t3));
    }
    const float2 w1 = make_float2(0.92387953251128674f, 0.38268343236508977f);
    const float2 w2 = make_float2(0.70710678118654752f, 0.70710678118654752f);
    const float2 w3 = make_float2(0.38268343236508977f, 0.92387953251128674f);
    const float2 w6 = make_float2(-0.70710678118654752f, 0.70710678118654752f);
    const float2 w9 = make_float2(-0.92387953251128674f, -0.38268343236508977f);
    s[5]  = cmul(s[5], w1);
    s[6]  = cmul(s[6], w2);
    s[7]  = cmul(s[7], w3);
    s[9]  = cmul(s[9], w2);
    s[10] = muli(s[10]);
    s[11] = cmul(s[11], w6);
    s[13] = cmul(s[13], w3);
    s[14] = cmul(s[14], w6);
    s[15] = cmul(s[15], w9);
#pragma unroll
    for (int al = 0; al < 4; ++al) {
        float2 x0 = s[4 * al + 0], x1 = s[4 * al + 1];
        float2 x2 = s[4 * al + 2], x3 = s[4 * al + 3];
        float2 t0 = cadd(x0, x2), t1 = csub(x0, x2);
        float2 t2 = cadd(x1, x3), t3 = csub(x1, x3);
        f[al]      = cadd(t0, t2);
        f[4 + al]  = cadd(t1, muli(t3));
        f[8 + al]  = csub(t0, t2);
        f[12 + al] = csub(t1, muli(t3));
    }
}

// Pass A tail: r[] holds W_{i*256+t}; fft16, twiddle E(t*k1/4096), store.
__device__ __forceinline__ void fftA_store(float2 r[16], float2* __restrict__ buf,
                                           const int t) {
    fft16(r);
    float sn, cs;
    __sincosf((float)t * TWOPI_4096, &sn, &cs);
    const float2 wb = make_float2(cs, sn);
    float2 w = wb;
#pragma unroll
    for (int k1 = 1; k1 < 16; ++k1) { r[k1] = cmul(r[k1], w); w = cmul(w, wb); }
#pragma unroll
    for (int i = 0; i < 16; ++i) buf[i * 256 + t] = r[i];
}

// Passes B and C on buf (A-output already stored). Leaves X[j2*256+t] in
// buf natural order. XOR-swizzled middle exchange (verified r2).
__device__ __forceinline__ void fft4096_tail(float2* __restrict__ buf, const int t) {
    float2 r[16];
    __syncthreads();  // (1) A writes -> B reads
    {
        const int k1 = t >> 4, m2 = t & 15;
        const int base = k1 * 256 + m2;
#pragma unroll
        for (int i = 0; i < 16; ++i) r[i] = buf[base + i * 16];
        fft16(r);
        float sn, cs;
        __sincosf((float)m2 * TWOPI_256, &sn, &cs);
        const float2 wb = make_float2(cs, sn);
        float2 w = wb;
#pragma unroll
        for (int j1 = 1; j1 < 16; ++j1) { r[j1] = cmul(r[j1], w); w = cmul(w, wb); }
        __syncthreads();  // (2) B reads -> B swizzled writes
        const int bw = k1 * 256 + (m2 ^ k1);
#pragma unroll
        for (int j1 = 0; j1 < 16; ++j1) buf[bw + j1 * 16] = r[j1];
    }
    __syncthreads();  // (3) B writes -> C reads
    {
        const int k1 = t & 15;
        const int bc = k1 * 256 + (t >> 4) * 16;
#pragma unroll
        for (int i = 0; i < 16; ++i) r[i] = buf[bc + (i ^ k1)];
        fft16(r);
        __syncthreads();  // (4) C reads -> natural-order writes
#pragma unroll
        for (int j2 = 0; j2 < 16; ++j2) buf[j2 * 256 + t] = r[j2];
    }
    __syncthreads();  // (5) C writes -> unpack reads
}

// ---- K1: DST-III along rows of x; writes panel-layout z ----
__global__ __launch_bounds__(256, 4) void dst_panel_k(const float* __restrict__ x,
                                                      float* __restrict__ z) {
    __shared__ float2 buf[4096];  // 32 KiB
    const int t = threadIdx.x;
    const int h = blockIdx.x;
    const int l = (h & 7) * 256 + (h >> 3);  // chunked XCD swizzle (bijective)
    const int p0 = 2 * l;
    const float* x0 = x + (size_t)p0 * NF;
    const float* x1 = x0 + NF;

    // pack directly into pass-A fragments: r[i] = W_{i*256+t}
    // W_k = [(x0[N-k]+x1[k]) + i(x1[N-k]-x0[k])] * 0.5*e^{i pi k/8192}, W_0=0
    float sn, cs;
    __sincosf((float)t * TWOPI_16384, &sn, &cs);
    float2 w = make_float2(0.5f * cs, 0.5f * sn);  // 1/2 folded in
    const float2 stp = make_float2(0.99518472667219693f, 0.09801714032956060f);
    float2 r[16];
#pragma unroll
    for (int i = 0; i < 16; ++i) {
        const int k = t + 256 * i;
        float2 ww = make_float2(0.f, 0.f);
        if (k > 0) {
            float re = x0[NF - k] + x1[k];
            float im = x1[NF - k] - x0[k];
            ww = make_float2(re * w.x - im * w.y, re * w.y + im * w.x);
        }
        r[i] = ww;
        w = cmul(w, stp);
    }
    fftA_store(r, buf, t);
    fft4096_tail(buf, t);

    // unpack with DST sign (scale already folded):
    //   z[p0][2n] = Re v_n, z[p0][2n+1] = -Re v_{4095-n}, row p1 from Im.
    // panel addr(p, v) = (v>>1)*8192 + 2p + (v&1) -> one float4 per n.
#pragma unroll
    for (int u = 0; u < 8; ++u) {
        const int n = t + 256 * u;
        float2 vn = buf[n];
        float2 vm = buf[NF - 1 - n];
        float4 q = make_float4(vn.x, -vm.x, vn.y, -vm.y);
        *(float4*)(z + (size_t)n * 8192 + 2 * p0) = q;
    }
}

// ---- K2: DCT-III along columns of z (panel layout); writes out ----
__global__ __launch_bounds__(256, 4) void dct_panel_k(const float* __restrict__ z,
                                                      float* __restrict__ out) {
    __shared__ float2 buf[4096];
    const int t = threadIdx.x;
    const int h = blockIdx.x;
    const int l = (h & 7) * 256 + (h >> 3);  // panel index vp = l
    const float* pz = z + (size_t)l * 8192;  // contiguous 32 KiB panel
    const float a0h = 0.5f * pz[0];          // 0.5*t0[0]
    const float a1h = 0.5f * pz[1];          // 0.5*t1[0]

    // pack: k=0: W_0 = (a0h, a1h)
    // k>0: W_k = [(t0[k]+t1[N-k]) + i(t1[k]-t0[N-k])] * 0.5*e^{i pi k/8192}
    //   where (t0[k],t1[k]) = float2 at pz+2k (fully coalesced).
    float sn, cs;
    __sincosf((float)t * TWOPI_16384, &sn, &cs);
    float2 w = make_float2(0.5f * cs, 0.5f * sn);
    const float2 stp = make_float2(0.99518472667219693f, 0.09801714032956060f);
    float2 r[16];
#pragma unroll
    for (int i = 0; i < 16; ++i) {
        const int k = t + 256 * i;
        if (k == 0) {
            r[i] = make_float2(a0h, a1h);
        } else {
            float2 f = *(const float2*)(pz + 2 * k);         // t0[k], t1[k]
            float2 g = *(const float2*)(pz + 2 * (NF - k));  // t0[N-k], t1[N-k]
            float re = f.x + g.y;
            float im = f.y - g.x;
            r[i] = make_float2(re * w.x - im * w.y, re * w.y + im * w.x);
        }
        w = cmul(w, stp);
    }
    fftA_store(r, buf, t);
    fft4096_tail(buf, t);

    // unpack: out[2n][v0..v0+1]   = (Re v_n + a0h, Im v_n + a1h)
    //         out[2n+1][v0..v0+1] = (Re v_{4095-n} + a0h, Im v_{4095-n} + a1h)
    const int v0 = 2 * l;
#pragma unroll
    for (int u = 0; u < 8; ++u) {
        const int n = t + 256 * u;
        float2 vn = buf[n];
        float2 vm = buf[NF - 1 - n];
        *(float2*)(out + (size_t)(2 * n) * NF + v0) =
            make_float2(vn.x + a0h, vn.y + a1h);
        *(float2*)(out + (size_t)(2 * n + 1) * NF + v0) =
            make_float2(vm.x + a0h, vm.y + a1h);
    }
}

extern "C" void kernel_launch(void* const* d_in, const int* in_sizes, int n_in,
                              void* d_out, int out_size, void* d_ws, size_t ws_size,
                              hipStream_t stream) {
    const float* x = (const float*)d_in[0];
    float* out = (float*)d_out;
    float* z = (float*)d_ws;  // 64 MiB panel-layout intermediate

    // z (panels) = row-DST3 of x
    dst_panel_k<<<2048, 256, 0, stream>>>(x, z);
    // out = column-DCT3 of z
    dct_panel_k<<<2048, 256, 0, stream>>>(z, out);
}

// Round 4
// 181.364 us; speedup vs baseline: 1.1812x; 1.1812x over previous
//
#include <hip/hip_runtime.h>

// IDCST2 via FFTs: out = C0 @ (x @ S1^T), M=N=4096, fp32.
//   DST-III rows:  s_v = (-1)^v * DCT3(reverse(x))_v  (c_0 = 0)
//   DCT-III via N-pt complex DFT (inverse Makhoul):
//     W_k = (c_k - i c_{N-k}) e^{i pi k/2N};  v = DFT_+(W)
//     y_{2n} = (Re v_n + c_0)/2 ; y_{2n+1} = (Re v_{N-1-n} + c_0)/2
//   v real => pack 2 rows per complex FFT (Re/Im). 1/2 folded into pack.
// FFT: radix-16 register FFT, 4096 = 16^3. Pass A entirely in registers
//   (pack fragment set == pass-A fragment set, same thread), then 2 LDS
//   exchanges (XOR-swizzled, conflict-free), 5 barriers, 32 KiB LDS
//   => 5 blocks/CU. LDS ops: 96 b64/thread (vs 128 with LDS-staged pack).
// Pipeline (ALL global access fully coalesced; r3 showed scattered 16B/8B
// stores cost ~3x partial-line writeback amplification => avoid):
//   dst_rows(x->ws) ; T(ws->out) ; dct_rows(out->ws) ; T(ws->out).

#define NF 4096
#define TWOPI_16384 3.8349519697141029e-4f  // 2*pi/16384
#define TWOPI_4096  1.5339807878856412e-3f  // 2*pi/4096
#define TWOPI_256   2.4543692606170259e-2f  // 2*pi/256

__device__ __forceinline__ float2 cmul(float2 a, float2 b) {
    return make_float2(a.x * b.x - a.y * b.y, a.x * b.y + a.y * b.x);
}
__device__ __forceinline__ float2 cadd(float2 a, float2 b) {
    return make_float2(a.x + b.x, a.y + b.y);
}
__device__ __forceinline__ float2 csub(float2 a, float2 b) {
    return make_float2(a.x - b.x, a.y - b.y);
}
__device__ __forceinline__ float2 muli(float2 a) {  // +i * a (positive-sign DFT)
    return make_float2(-a.y, a.x);
}

// 16-point DFT_+ in registers, natural order in/out (verified r2/r3).
__device__ __forceinline__ void fft16(float2 f[16]) {
    float2 s[16];
#pragma unroll
    for (int b = 0; b < 4; ++b) {
        float2 x0 = f[b], x1 = f[b + 4], x2 = f[b + 8], x3 = f[b + 12];
        float2 t0 = cadd(x0, x2), t1 = csub(x0, x2);
        float2 t2 = cadd(x1, x3), t3 = csub(x1, x3);
        s[b]      = cadd(t0, t2);
        s[4 + b]  = cadd(t1, muli(t3));
        s[8 + b]  = csub(t0, t2);
        s[12 + b] = csub(t1, muli(t3));
    }
    const float2 w1 = make_float2(0.92387953251128674f, 0.38268343236508977f);
    const float2 w2 = make_float2(0.70710678118654752f, 0.70710678118654752f);
    const float2 w3 = make_float2(0.38268343236508977f, 0.92387953251128674f);
    const float2 w6 = make_float2(-0.70710678118654752f, 0.70710678118654752f);
    const float2 w9 = make_float2(-0.92387953251128674f, -0.38268343236508977f);
    s[5]  = cmul(s[5], w1);
    s[6]  = cmul(s[6], w2);
    s[7]  = cmul(s[7], w3);
    s[9]  = cmul(s[9], w2);
    s[10] = muli(s[10]);
    s[11] = cmul(s[11], w6);
    s[13] = cmul(s[13], w3);
    s[14] = cmul(s[14], w6);
    s[15] = cmul(s[15], w9);
#pragma unroll
    for (int al = 0; al < 4; ++al) {
        float2 x0 = s[4 * al + 0], x1 = s[4 * al + 1];
        float2 x2 = s[4 * al + 2], x3 = s[4 * al + 3];
        float2 t0 = cadd(x0, x2), t1 = csub(x0, x2);
        float2 t2 = cadd(x1, x3), t3 = csub(x1, x3);
        f[al]      = cadd(t0, t2);
        f[4 + al]  = cadd(t1, muli(t3));
        f[8 + al]  = csub(t0, t2);
        f[12 + al] = csub(t1, muli(t3));
    }
}

// Pass A tail: r[] holds W_{i*256+t}; fft16, twiddle E(t*k1/4096), store.
__device__ __forceinline__ void fftA_store(float2 r[16], float2* __restrict__ buf,
                                           const int t) {
    fft16(r);
    float sn, cs;
    __sincosf((float)t * TWOPI_4096, &sn, &cs);
    const float2 wb = make_float2(cs, sn);
    float2 w = wb;
#pragma unroll
    for (int k1 = 1; k1 < 16; ++k1) { r[k1] = cmul(r[k1], w); w = cmul(w, wb); }
#pragma unroll
    for (int i = 0; i < 16; ++i) buf[i * 256 + t] = r[i];
}

// Passes B and C (A-output already in buf). Leaves X natural order.
// XOR-swizzled middle exchange: D[k1,j1,m2] at k1*256 + j1*16 + (m2^k1).
__device__ __forceinline__ void fft4096_tail(float2* __restrict__ buf, const int t) {
    float2 r[16];
    __syncthreads();  // (1) A writes -> B reads
    {
        const int k1 = t >> 4, m2 = t & 15;
        const int base = k1 * 256 + m2;
#pragma unroll
        for (int i = 0; i < 16; ++i) r[i] = buf[base + i * 16];
        fft16(r);
        float sn, cs;
        __sincosf((float)m2 * TWOPI_256, &sn, &cs);
        const float2 wb = make_float2(cs, sn);
        float2 w = wb;
#pragma unroll
        for (int j1 = 1; j1 < 16; ++j1) { r[j1] = cmul(r[j1], w); w = cmul(w, wb); }
        __syncthreads();  // (2) B reads -> B swizzled writes
        const int bw = k1 * 256 + (m2 ^ k1);
#pragma unroll
        for (int j1 = 0; j1 < 16; ++j1) buf[bw + j1 * 16] = r[j1];
    }
    __syncthreads();  // (3) B writes -> C reads
    {
        const int k1 = t & 15;
        const int bc = k1 * 256 + (t >> 4) * 16;
#pragma unroll
        for (int i = 0; i < 16; ++i) r[i] = buf[bc + (i ^ k1)];
        fft16(r);
        __syncthreads();  // (4) C reads -> natural-order writes
#pragma unroll
        for (int j2 = 0; j2 < 16; ++j2) buf[j2 * 256 + t] = r[j2];
    }
    __syncthreads();  // (5) C writes -> unpack reads
}

// ---- stage 1: DST-III along rows; two rows per block ----
__global__ __launch_bounds__(256) void dst_rows_k(const float* __restrict__ x,
                                                  float* __restrict__ y) {
    __shared__ float2 buf[4096];  // 32 KiB -> 5 blocks/CU
    const int t = threadIdx.x;
    const size_t r0 = (size_t)blockIdx.x * 2;
    const float* x0 = x + r0 * NF;
    const float* x1 = x0 + NF;

    // pack directly into pass-A fragments r[i] = W_{i*256+t}:
    // W_k = [(x0[N-k]+x1[k]) + i(x1[N-k]-x0[k])] * 0.5*e^{i pi k/8192}, W_0=0
    float sn, cs;
    __sincosf((float)t * TWOPI_16384, &sn, &cs);
    float2 w = make_float2(0.5f * cs, 0.5f * sn);  // 1/2 folded in
    const float2 stp = make_float2(0.99518472667219693f, 0.09801714032956060f);
    float2 r[16];
#pragma unroll
    for (int i = 0; i < 16; ++i) {
        const int k = t + 256 * i;
        float2 ww = make_float2(0.f, 0.f);
        if (k > 0) {
            float re = x0[NF - k] + x1[k];
            float im = x1[NF - k] - x0[k];
            ww = make_float2(re * w.x - im * w.y, re * w.y + im * w.x);
        }
        r[i] = ww;
        w = cmul(w, stp);
    }
    fftA_store(r, buf, t);
    fft4096_tail(buf, t);

    // unpack with DST sign (scale folded): y[2n] = Re v_n, y[2n+1] = -Re v_{N-1-n}
    float* y0 = y + r0 * NF;
    float* y1 = y0 + NF;
#pragma unroll
    for (int u = 0; u < 8; ++u) {
        const int n = t + 256 * u;
        float2 vn = buf[n];
        float2 vm = buf[NF - 1 - n];
        ((float2*)y0)[n] = make_float2(vn.x, -vm.x);
        ((float2*)y1)[n] = make_float2(vn.y, -vm.y);
    }
}

// ---- stage 2: DCT-III along rows of yT; two rows per block ----
__global__ __launch_bounds__(256) void dct_rows_k(const float* __restrict__ yt,
                                                  float* __restrict__ ot) {
    __shared__ float2 buf[4096];
    const int t = threadIdx.x;
    const size_t r0 = (size_t)blockIdx.x * 2;
    const float* t0 = yt + r0 * NF;
    const float* t1 = t0 + NF;
    const float a0h = 0.5f * t0[0];
    const float a1h = 0.5f * t1[0];

    // pack (c_N := 0): k=0: W_0 = 0.5*(c0 + i c'0)
    // k>0: W_k = [(t0[k]+t1[N-k]) + i(t1[k]-t0[N-k])] * 0.5*e^{i pi k/8192}
    float sn, cs;
    __sincosf((float)t * TWOPI_16384, &sn, &cs);
    float2 w = make_float2(0.5f * cs, 0.5f * sn);
    const float2 stp = make_float2(0.99518472667219693f, 0.09801714032956060f);
    float2 r[16];
#pragma unroll
    for (int i = 0; i < 16; ++i) {
        const int k = t + 256 * i;
        if (k == 0) {
            r[i] = make_float2(a0h, a1h);
        } else {
            float re = t0[k] + t1[NF - k];
            float im = t1[k] - t0[NF - k];
            r[i] = make_float2(re * w.x - im * w.y, re * w.y + im * w.x);
        }
        w = cmul(w, stp);
    }
    fftA_store(r, buf, t);
    fft4096_tail(buf, t);

    // unpack (scale folded): o[2n] = Re v_n + a0h, o[2n+1] = Re v_{N-1-n} + a0h
    float* o0 = ot + r0 * NF;
    float* o1 = o0 + NF;
#pragma unroll
    for (int u = 0; u < 8; ++u) {
        const int n = t + 256 * u;
        float2 vn = buf[n];
        float2 vm = buf[NF - 1 - n];
        ((float2*)o0)[n] = make_float2(vn.x + a0h, vm.x + a0h);
        ((float2*)o1)[n] = make_float2(vn.y + a1h, vm.y + a1h);
    }
}

// ---- 32x32 LDS-tiled transpose, float4 IO: out[c][r] = in[r][c] ----
__global__ __launch_bounds__(256) void transpose_k(const float* __restrict__ in,
                                                   float* __restrict__ out) {
    __shared__ float tile[32][33];
    const int tx = threadIdx.x;  // 0..7
    const int ty = threadIdx.y;  // 0..31
    const int c0 = blockIdx.x * 32;
    const int r0 = blockIdx.y * 32;

    float4 v = *(const float4*)(in + (size_t)(r0 + ty) * NF + c0 + 4 * tx);
    tile[ty][4 * tx + 0] = v.x;
    tile[ty][4 * tx + 1] = v.y;
    tile[ty][4 * tx + 2] = v.z;
    tile[ty][4 * tx + 3] = v.w;
    __syncthreads();

    float4 o;
    o.x = tile[4 * tx + 0][ty];
    o.y = tile[4 * tx + 1][ty];
    o.z = tile[4 * tx + 2][ty];
    o.w = tile[4 * tx + 3][ty];
    *(float4*)(out + (size_t)(c0 + ty) * NF + r0 + 4 * tx) = o;
}

extern "C" void kernel_launch(void* const* d_in, const int* in_sizes, int n_in,
                              void* d_out, int out_size, void* d_ws, size_t ws_size,
                              hipStream_t stream) {
    const float* x = (const float*)d_in[0];
    float* out = (float*)d_out;
    float* y = (float*)d_ws;  // 64 MiB scratch

    dim3 tgrid(128, 128), tblk(8, 32);

    // y[p,v] = DST3 rows of x
    dst_rows_k<<<2048, 256, 0, stream>>>(x, y);
    // out = yT
    transpose_k<<<tgrid, tblk, 0, stream>>>(y, out);
    // y[v,u] = DCT3 rows of yT  (= out[u,v] transposed)
    dct_rows_k<<<2048, 256, 0, stream>>>(out, y);
    // out[u,v]
    transpose_k<<<tgrid, tblk, 0, stream>>>(y, out);
}